// Round 16
// baseline (36.949 us; speedup 1.0000x reference)
//
#include <hip/hip_runtime.h>

#define Nn 1024
#define Cc 23
#define Hh 100
#define KN 64                  // knots over v=r/1.5 in [0,3], 63 cells
#define DSTR 68                // lds_d row stride (64 + pad)
#define MUSCALE 14.0f          // (63/3)/1.5  (mu = r * MUSCALE)
#define MUCLAMP 62.999f
#define NBC 2048               // conv blocks: z(4) x ah(8) x s(64)

// ws float offsets
#define UT_OFF     0           // U transposed [23][64] = 1472
#define WF1T_OFF   1536        // Wf1^T / 32  [30][1024] = 30720
#define BIAS_OFF   32256       // [4]
#define COLSUM_OFF 32260       // [30]
#define D_OFF      32320       // D[4096][64] = 262144
#define PB_OFF     294464      // [30][2048] fc1 partials = 61440

__device__ __forceinline__ float rdlane(float v, int l) {
    return __int_as_float(__builtin_amdgcn_readlane(__float_as_int(v), l));
}

// ---------------------------------------------------------------------------
// K0: UT only — 64 blocks, one knot each. U_T[c][k] = sum_h relu(g_h(v_k))*W2[h][c]
// ---------------------------------------------------------------------------
__global__ __launch_bounds__(256)
void ut_kernel(const float* __restrict__ W1,
               const float* __restrict__ b1,
               const float* __restrict__ W2,
               float* __restrict__ ws) {
    __shared__ float w2s[Hh * Cc];
    __shared__ float hv_s[Hh];
    int k = blockIdx.x;
    int t = threadIdx.x;
    for (int j = t; j < Hh * Cc; j += 256) w2s[j] = W2[j];
    if (t < Hh) {
        float v = (float)k * (3.0f / 63.0f);
        const float HPI = 1.57079632679f;
        float c0 = cosf(HPI * v);
        float c1 = cosf(HPI * (v - 1.0f));
        float c2 = cosf(HPI * (v - 2.0f));
        float s0 = (v < 1.0f) ? c0 * c0 : 0.0f;
        float s1 = (fabsf(v - 1.0f) < 1.0f) ? c1 * c1 : 0.0f;
        float s2 = (v > 1.0f && v < 3.0f) ? c2 * c2 : 0.0f;
        float pre = fmaf(s0, W1[t],
                     fmaf(s1, W1[Hh + t],
                      fmaf(s2, W1[2 * Hh + t], b1[t])));
        hv_s[t] = fmaxf(pre, 0.f);
    }
    __syncthreads();
    if (t < Cc) {
        float a0 = 0.f, a1 = 0.f;
        #pragma unroll 4
        for (int h = 0; h < Hh; h += 2) {
            a0 = fmaf(hv_s[h],     w2s[h * Cc + t],       a0);
            a1 = fmaf(hv_s[h + 1], w2s[(h + 1) * Cc + t], a1);
        }
        ws[UT_OFF + t * KN + k] = a0 + a1;
    }
}

// ---------------------------------------------------------------------------
// K1: dgemm + all UT-independent prep. 291 blocks x 256 thr.
//  0..255 : dgemm — D[row][k] = sum_c UT[c][k]*f[row][c], 16 rows/block
//  256..259: bias[z]
//  260    : colsum[d]
//  261..290: Wf1T[d][k] = Wf1[k][d]/32
// ---------------------------------------------------------------------------
__global__ __launch_bounds__(256)
void aux_kernel(const float* __restrict__ f,
                const float* __restrict__ W1,   // unused, uniform signature
                const float* __restrict__ b2,
                const float* __restrict__ Wf1,
                float* __restrict__ ws) {
    int blk = blockIdx.x;
    int t = threadIdx.x;
    if (blk < 256) {                       // dgemm
        const int lane = t & 63;
        const int wv = __builtin_amdgcn_readfirstlane(t >> 6);
        const float* ut = ws + UT_OFF;
        float ur[Cc];
        #pragma unroll
        for (int c = 0; c < Cc; ++c) ur[c] = ut[c * KN + lane];
        const int row0 = blk * 16 + wv * 4;
        float fr[2];                       // 4 rows x 23 = 92 floats
        {
            int base = row0 * Cc;
            fr[0] = f[base + lane];
            int o2 = 64 + lane; if (o2 > 91) o2 = 91;
            fr[1] = f[base + o2];
        }
        float* D = ws + D_OFF;
        #pragma unroll
        for (int r = 0; r < 4; ++r) {
            float a0 = 0.f, a1 = 0.f, a2 = 0.f, a3 = 0.f;
            #pragma unroll
            for (int c = 0; c < 20; c += 4) {
                a0 = fmaf(rdlane(fr[(r * Cc + c + 0) >> 6], (r * Cc + c + 0) & 63), ur[c + 0], a0);
                a1 = fmaf(rdlane(fr[(r * Cc + c + 1) >> 6], (r * Cc + c + 1) & 63), ur[c + 1], a1);
                a2 = fmaf(rdlane(fr[(r * Cc + c + 2) >> 6], (r * Cc + c + 2) & 63), ur[c + 2], a2);
                a3 = fmaf(rdlane(fr[(r * Cc + c + 3) >> 6], (r * Cc + c + 3) & 63), ur[c + 3], a3);
            }
            a0 = fmaf(rdlane(fr[(r * Cc + 20) >> 6], (r * Cc + 20) & 63), ur[20], a0);
            a1 = fmaf(rdlane(fr[(r * Cc + 21) >> 6], (r * Cc + 21) & 63), ur[21], a1);
            a2 = fmaf(rdlane(fr[(r * Cc + 22) >> 6], (r * Cc + 22) & 63), ur[22], a2);
            D[(row0 + r) * KN + lane] = (a0 + a1) + (a2 + a3);
        }
    } else if (blk < 260) {                // bias[z]
        __shared__ float red[256];
        int z = blk - 256;
        float s = 0.f;
        #pragma unroll
        for (int rr = 0; rr < 4; ++rr) {
            const float* fr = f + ((z << 10) + rr * 256 + t) * Cc;
            #pragma unroll
            for (int c = 0; c < Cc; ++c) s = fmaf(fr[c], b2[c], s);
        }
        red[t] = s; __syncthreads();
        for (int off = 128; off; off >>= 1) {
            if (t < off) red[t] += red[t + off];
            __syncthreads();
        }
        if (t == 0) ws[BIAS_OFF + z] = red[0];
    } else if (blk == 260) {               // colsum[d]
        __shared__ float cs_s[240];
        if (t < 240) {
            int d = t % 30, oct = t / 30;
            float c0 = 0.f, c1 = 0.f;
            #pragma unroll 4
            for (int j = 0; j < 128; j += 2) {
                c0 += Wf1[(oct * 128 + j) * 30 + d];
                c1 += Wf1[(oct * 128 + j + 1) * 30 + d];
            }
            cs_s[t] = c0 + c1;
        }
        __syncthreads();
        if (t < 30) {
            float cs = 0.f;
            #pragma unroll
            for (int o = 0; o < 8; ++o) cs += cs_s[o * 30 + t];
            ws[COLSUM_OFF + t] = cs;
        }
    } else {                               // Wf1T, one d per block
        int d = blk - 261;
        #pragma unroll
        for (int j = 0; j < 4; ++j) {
            int k = j * 256 + t;
            ws[WF1T_OFF + d * Nn + k] = Wf1[k * 30 + d] * 0.03125f;
        }
    }
}

// ---------------------------------------------------------------------------
// K2: conv + fc1 fold. 2048 blocks x 128 thr (8 blocks/CU).
// Block (z, ah, s): a-range ah*128..+127 (1/thread), b-range s*16..+15.
// ---------------------------------------------------------------------------
__global__ __launch_bounds__(128, 4)
void conv_kernel(const float* __restrict__ geom,
                 const float* __restrict__ Dg,       // ws + D_OFF
                 const float2* __restrict__ wf1t2,   // ws + WF1T_OFF
                 float* __restrict__ pb) {           // ws + PB_OFF
    __shared__ float lds_d[16 * DSTR];   // 4352 B
    __shared__ float lds_acc[128];
    const int bid = blockIdx.x;
    const int t = threadIdx.x;
    const int lane = t & 63;
    const int wv = __builtin_amdgcn_readfirstlane(t >> 6);
    const int z = bid >> 9;
    const int ah = (bid >> 6) & 7;
    const int s = bid & 63;
    const int b0 = s * 16;

    // stage D-tile: 16 rows x 16 float4, 2 rounds, coalesced
    {
        const float4* src = reinterpret_cast<const float4*>(Dg + ((z << 10) + b0) * KN);
        #pragma unroll
        for (int j = t; j < 256; j += 128) {
            int row = j >> 4, k4 = j & 15;
            reinterpret_cast<float4*>(lds_d)[row * 17 + k4] = src[j];
        }
    }
    float gr;                              // 16 b-geometries (48 floats)
    {
        int off = lane < 48 ? lane : 47;
        gr = geom[((z << 10) + b0) * 3 + off];
    }
    // a-geometry raw (stride-12 dword loads, L2-hot)
    const int ag = (z << 10) + (ah << 7) + t;
    float gax = geom[ag * 3], gay = geom[ag * 3 + 1], gaz = geom[ag * 3 + 2];
    __syncthreads();

    // edges: thread owns a = ah*128 + t; 16 b's
    float acc = 0.f;
    #pragma unroll
    for (int bl = 0; bl < 16; ++bl) {
        float dx = gax - rdlane(gr, bl * 3 + 0);
        float dy = gay - rdlane(gr, bl * 3 + 1);
        float dz = gaz - rdlane(gr, bl * 3 + 2);
        float r = sqrtf(fmaf(dx, dx, fmaf(dy, dy, fmaf(dz, dz, 1e-12f))));
        float mu = fminf(r * MUSCALE, MUCLAMP);
        int m = (int)mu;
        float tt = mu - (float)m;
        const float* row = lds_d + bl * DSTR + m;
        float d0 = row[0];
        float d1 = row[1];
        acc += fmaf(tt, d1 - d0, d0);
    }
    lds_acc[t] = acc;
    __syncthreads();

    // fold: wave wv handles d = wv*15..+14; lane covers 2 a's; plain stores
    {
        const float2* a2 = reinterpret_cast<const float2*>(lds_acc);
        float2 av = a2[lane];
        #pragma unroll
        for (int i = 0; i < 15; ++i) {
            int d = wv * 15 + i;
            float2 w = wf1t2[d * 512 + (ah << 6) + lane];
            float sum = av.x * w.x + av.y * w.y;
            #pragma unroll
            for (int off = 32; off; off >>= 1) sum += __shfl_down(sum, off);
            if (lane == 0) pb[d * NBC + (z << 9) + (ah << 6) + s] = sum;
        }
    }
}

// ---------------------------------------------------------------------------
// K3: head — one 512-thread block. 480-way pb reduction, fc1, fc2, fc3.
// ---------------------------------------------------------------------------
__global__ __launch_bounds__(512)
void head_kernel(const float* __restrict__ ws,
                 const float* __restrict__ bf1,
                 const float* __restrict__ Wf2, const float* __restrict__ bf2,
                 const float* __restrict__ Wf3, const float* __restrict__ bf3,
                 float* __restrict__ out) {
    __shared__ float tb[480];
    __shared__ float x1s[120];
    __shared__ float x2s[40];
    int t = threadIdx.x;
    if (t < 480) {                         // (d, z, quarter): 128 pb floats
        int d = t >> 4, rem = t & 15;
        int z = rem >> 2, q = rem & 3;
        const float4* p4 = reinterpret_cast<const float4*>(
            ws + PB_OFF + d * NBC + (z << 9) + q * 128);
        float s0 = 0.f, s1 = 0.f, s2 = 0.f, s3 = 0.f;
        #pragma unroll
        for (int j = 0; j < 32; ++j) {
            float4 v = p4[j];
            s0 += v.x; s1 += v.y; s2 += v.z; s3 += v.w;
        }
        tb[t] = (s0 + s1) + (s2 + s3);
    }
    __syncthreads();
    if (t < 120) {                         // t = d*4 + z
        int d = t >> 2, zz = t & 3;
        int base = d * 16 + zz * 4;
        float x1 = ((tb[base] + tb[base + 1]) + (tb[base + 2] + tb[base + 3]))
                 + ws[BIAS_OFF + zz] * 0.03125f * ws[COLSUM_OFF + d]
                 + bf1[d];
        x1s[zz * 30 + d] = fmaxf(x1, 0.f);
    }
    __syncthreads();
    if (t < 40) {
        int zz = t / 10, d = t % 10;
        float sm = bf2[d];
        #pragma unroll
        for (int kk = 0; kk < 30; ++kk)
            sm = fmaf(x1s[zz * 30 + kk], Wf2[kk * 10 + d], sm);
        x2s[t] = fmaxf(sm, 0.f);
    }
    __syncthreads();
    if (t < 4) {
        float sm = bf3[0];
        #pragma unroll
        for (int kk = 0; kk < 10; ++kk)
            sm = fmaf(x2s[t * 10 + kk], Wf3[kk], sm);
        out[t] = sm;
    }
}

extern "C" void kernel_launch(void* const* d_in, const int* in_sizes, int n_in,
                              void* d_out, int out_size, void* d_ws, size_t ws_size,
                              hipStream_t stream) {
    const float* f   = (const float*)d_in[0];
    const float* geo = (const float*)d_in[1];
    const float* W1  = (const float*)d_in[2];
    const float* b1  = (const float*)d_in[3];
    const float* W2  = (const float*)d_in[4];
    const float* b2  = (const float*)d_in[5];
    const float* Wf1 = (const float*)d_in[6];
    const float* bf1 = (const float*)d_in[7];
    const float* Wf2 = (const float*)d_in[8];
    const float* bf2 = (const float*)d_in[9];
    const float* Wf3 = (const float*)d_in[10];
    const float* bf3 = (const float*)d_in[11];
    float* ws  = (float*)d_ws;
    float* out = (float*)d_out;

    hipLaunchKernelGGL(ut_kernel, dim3(64), dim3(256), 0, stream,
                       W1, b1, W2, ws);
    hipLaunchKernelGGL(aux_kernel, dim3(291), dim3(256), 0, stream,
                       f, W1, b2, Wf1, ws);
    hipLaunchKernelGGL(conv_kernel, dim3(NBC), dim3(128), 0, stream,
                       geo, ws + D_OFF,
                       reinterpret_cast<const float2*>(ws + WF1T_OFF),
                       ws + PB_OFF);
    hipLaunchKernelGGL(head_kernel, dim3(1), dim3(512), 0, stream,
                       ws, bf1, Wf2, bf2, Wf3, bf3, out);
}

// Round 17
// 23.211 us; speedup vs baseline: 1.5919x; 1.5919x over previous
//
#include <hip/hip_runtime.h>

#define Nn 1024
#define Cc 23
#define Hh 100
#define KN 64                  // knots over v=r/1.5 in [0,3], 63 cells
#define DSTR 68                // lds_d row stride (64 + pad)
#define MUSCALE 14.0f          // (63/3)/1.5  (mu = r * MUSCALE)
#define MUCLAMP 62.999f
#define NBC 512                // conv blocks: z(4) x ah(2) x s(64)
#define NHB 30                 // head blocks

// ws float offsets
#define UT_OFF     0           // U transposed [23][64] = 1472
#define WF1T_OFF   1536        // Wf1^T / 32  [30][1024] = 30720
#define BIAS_OFF   32256       // [4]
#define COLSUM_OFF 32260       // [30]
#define CTR_OFF    32320       // 1 uint ticket (64B-aligned)
#define X1PRE_OFF  32384       // [30][4]
#define PB_OFF     32512       // [30][512] fc1 partials = 15360

__device__ __forceinline__ float rdlane(float v, int l) {
    return __int_as_float(__builtin_amdgcn_readlane(__float_as_int(v), l));
}

// ---------------------------------------------------------------------------
// K0: prep — 99 blocks.
//  0..63 : U_T[c][k] (one knot per block; W2 LDS-staged, coalesced)
//  64..93: Wf1T[d][k] = Wf1[k][d]/32
//  94..97: bias[z]
//  98    : colsum[d] + zero ticket
// ---------------------------------------------------------------------------
__global__ __launch_bounds__(256)
void prep_kernel(const float* __restrict__ f,
                 const float* __restrict__ W1,
                 const float* __restrict__ b1,
                 const float* __restrict__ W2,
                 const float* __restrict__ b2,
                 const float* __restrict__ Wf1,
                 float* __restrict__ ws) {
    int blk = blockIdx.x;
    int t = threadIdx.x;
    if (blk < 64) {                        // one knot per block
        __shared__ float w2s[Hh * Cc];
        __shared__ float hv_s[Hh];
        int k = blk;
        for (int j = t; j < Hh * Cc; j += 256) w2s[j] = W2[j];
        if (t < Hh) {
            float v = (float)k * (3.0f / 63.0f);
            const float HPI = 1.57079632679f;
            float c0 = cosf(HPI * v);
            float c1 = cosf(HPI * (v - 1.0f));
            float c2 = cosf(HPI * (v - 2.0f));
            float s0 = (v < 1.0f) ? c0 * c0 : 0.0f;
            float s1 = (fabsf(v - 1.0f) < 1.0f) ? c1 * c1 : 0.0f;
            float s2 = (v > 1.0f && v < 3.0f) ? c2 * c2 : 0.0f;
            float pre = fmaf(s0, W1[t],
                         fmaf(s1, W1[Hh + t],
                          fmaf(s2, W1[2 * Hh + t], b1[t])));
            hv_s[t] = fmaxf(pre, 0.f);
        }
        __syncthreads();
        if (t < Cc) {
            float a0 = 0.f, a1 = 0.f;
            #pragma unroll 4
            for (int h = 0; h < Hh; h += 2) {
                a0 = fmaf(hv_s[h],     w2s[h * Cc + t],       a0);
                a1 = fmaf(hv_s[h + 1], w2s[(h + 1) * Cc + t], a1);
            }
            ws[UT_OFF + t * KN + k] = a0 + a1;
        }
    } else if (blk < 94) {                 // Wf1T, one d per block
        int d = blk - 64;
        #pragma unroll
        for (int j = 0; j < 4; ++j) {
            int k = j * 256 + t;
            ws[WF1T_OFF + d * Nn + k] = Wf1[k * 30 + d] * 0.03125f;
        }
    } else if (blk < 98) {                 // bias[z]
        __shared__ float red[256];
        int z = blk - 94;
        float s = 0.f;
        #pragma unroll
        for (int rr = 0; rr < 4; ++rr) {
            const float* fr = f + ((z << 10) + rr * 256 + t) * Cc;
            #pragma unroll
            for (int c = 0; c < Cc; ++c) s = fmaf(fr[c], b2[c], s);
        }
        red[t] = s; __syncthreads();
        for (int off = 128; off; off >>= 1) {
            if (t < off) red[t] += red[t + off];
            __syncthreads();
        }
        if (t == 0) ws[BIAS_OFF + z] = red[0];
    } else {                               // colsum[d] + ticket zero
        __shared__ float cs_s[240];
        if (t < 240) {
            int d = t % 30, oct = t / 30;
            float c0 = 0.f, c1 = 0.f;
            #pragma unroll 4
            for (int j = 0; j < 128; j += 2) {
                c0 += Wf1[(oct * 128 + j) * 30 + d];
                c1 += Wf1[(oct * 128 + j + 1) * 30 + d];
            }
            cs_s[t] = c0 + c1;
        }
        __syncthreads();
        if (t < 30) {
            float cs = 0.f;
            #pragma unroll
            for (int o = 0; o < 8; ++o) cs += cs_s[o * 30 + t];
            ws[COLSUM_OFF + t] = cs;
        }
        if (t == 0) reinterpret_cast<unsigned*>(ws + CTR_OFF)[0] = 0u;
    }
}

// ---------------------------------------------------------------------------
// K1: conv. 512 blocks x 256 thr. Block (z, ah, s): a-range ah*512..+511
// (2 a's/thread), b-range s*16..+15. Per-block D-build (readlane f
// broadcasts — no dgemm kernel, no D round-trip), 32 lerp-edges/thread,
// fold through Wf1T -> plain stores pb[d][bid].
// ---------------------------------------------------------------------------
__global__ __launch_bounds__(256, 2)
void conv_kernel(const float* __restrict__ f,
                 const float* __restrict__ geom,
                 const float* __restrict__ ut,       // ws + UT_OFF
                 const float4* __restrict__ wf1t4,   // ws + WF1T_OFF
                 float* __restrict__ pb) {           // ws + PB_OFF
    __shared__ float lds_d[16 * DSTR];   // 4352 B (aliased: acc staging)
    const int bid = blockIdx.x;
    const int t = threadIdx.x;
    const int lane = t & 63;
    const int q = __builtin_amdgcn_readfirstlane(t >> 6);   // wave/quarter 0..3
    const int z = bid >> 7;
    const int ah = (bid >> 6) & 1;
    const int s = bid & 63;
    const int b0 = s * 16;
    const int k = lane;                    // knot = lane (KN=64)

    // staging (all coalesced / per-lane)
    float ur[Cc];
    #pragma unroll
    for (int c = 0; c < Cc; ++c) ur[c] = ut[c * KN + k];
    float fr[2];                           // quarter's 4 rows x 23 = 92 floats
    {
        int base = ((z << 10) + b0 + q * 4) * Cc;
        fr[0] = f[base + lane];
        int o2 = 64 + lane; if (o2 > 91) o2 = 91;
        fr[1] = f[base + o2];
    }
    float gr;                              // 16 b-geometries (48 floats)
    {
        int off = lane < 48 ? lane : 47;
        gr = geom[((z << 10) + b0) * 3 + off];
    }
    int ag0 = ((z << 10) + (ah << 9) + t) * 3;
    float gax0 = geom[ag0], gay0 = geom[ag0 + 1], gaz0 = geom[ag0 + 2];
    int ag1 = ag0 + 768;                   // +256 nodes
    float gax1 = geom[ag1], gay1 = geom[ag1 + 1], gaz1 = geom[ag1 + 2];

    // D-build: quarter q does rows q*4..+3; f broadcast via readlane
    #pragma unroll
    for (int r = 0; r < 4; ++r) {
        float a0 = 0.f, a1 = 0.f, a2 = 0.f, a3 = 0.f;
        #pragma unroll
        for (int c = 0; c < 20; c += 4) {
            a0 = fmaf(rdlane(fr[(r * Cc + c + 0) >> 6], (r * Cc + c + 0) & 63), ur[c + 0], a0);
            a1 = fmaf(rdlane(fr[(r * Cc + c + 1) >> 6], (r * Cc + c + 1) & 63), ur[c + 1], a1);
            a2 = fmaf(rdlane(fr[(r * Cc + c + 2) >> 6], (r * Cc + c + 2) & 63), ur[c + 2], a2);
            a3 = fmaf(rdlane(fr[(r * Cc + c + 3) >> 6], (r * Cc + c + 3) & 63), ur[c + 3], a3);
        }
        a0 = fmaf(rdlane(fr[(r * Cc + 20) >> 6], (r * Cc + 20) & 63), ur[20], a0);
        a1 = fmaf(rdlane(fr[(r * Cc + 21) >> 6], (r * Cc + 21) & 63), ur[21], a1);
        a2 = fmaf(rdlane(fr[(r * Cc + 22) >> 6], (r * Cc + 22) & 63), ur[22], a2);
        lds_d[(q * 4 + r) * DSTR + k] = (a0 + a1) + (a2 + a3);
    }
    __syncthreads();

    // edges: 2 a's x 16 b's per thread
    float acc0 = 0.f, acc1 = 0.f;
    #pragma unroll
    for (int bl = 0; bl < 16; ++bl) {
        float gbx = rdlane(gr, bl * 3 + 0);
        float gby = rdlane(gr, bl * 3 + 1);
        float gbz = rdlane(gr, bl * 3 + 2);
        const float* row = lds_d + bl * DSTR;
        {
            float dx = gax0 - gbx, dy = gay0 - gby, dz = gaz0 - gbz;
            float r = sqrtf(fmaf(dx, dx, fmaf(dy, dy, fmaf(dz, dz, 1e-12f))));
            float mu = fminf(r * MUSCALE, MUCLAMP);
            int m = (int)mu;
            float tt = mu - (float)m;
            float d0 = row[m], d1 = row[m + 1];
            acc0 += fmaf(tt, d1 - d0, d0);
        }
        {
            float dx = gax1 - gbx, dy = gay1 - gby, dz = gaz1 - gbz;
            float r = sqrtf(fmaf(dx, dx, fmaf(dy, dy, fmaf(dz, dz, 1e-12f))));
            float mu = fminf(r * MUSCALE, MUCLAMP);
            int m = (int)mu;
            float tt = mu - (float)m;
            float d0 = row[m], d1 = row[m + 1];
            acc1 += fmaf(tt, d1 - d0, d0);
        }
    }
    __syncthreads();

    // fold: 512 accs -> 30 per-block partials via Wf1T, plain stores
    lds_d[t] = acc0;
    lds_d[256 + t] = acc1;
    __syncthreads();
    {
        const float4* a4 = reinterpret_cast<const float4*>(lds_d);
        float4 av0 = a4[lane];                    // a-local 4*lane..+3
        float4 av1 = a4[64 + lane];               // a-local 256+4*lane..+3
        #pragma unroll
        for (int i = 0; i < 8; ++i) {
            int d = q + 4 * i;
            if (d < 30) {
                float4 w0 = wf1t4[d * 256 + (ah << 7) + lane];
                float4 w1 = wf1t4[d * 256 + (ah << 7) + 64 + lane];
                float sum = av0.x * w0.x + av0.y * w0.y + av0.z * w0.z + av0.w * w0.w
                          + av1.x * w1.x + av1.y * w1.y + av1.z * w1.z + av1.w * w1.w;
                #pragma unroll
                for (int off = 32; off; off >>= 1) sum += __shfl_down(sum, off);
                if (lane == 0) pb[d * NBC + bid] = sum;
            }
        }
    }
}

// ---------------------------------------------------------------------------
// K2: head — 30 blocks (one d each). Wave w = z: reduce 128 pb floats ->
// x1pre[d][z]. 30-way ticket; last block runs fc1-bias/relu + fc2 + fc3.
// ---------------------------------------------------------------------------
__global__ __launch_bounds__(256)
void head_kernel(float* __restrict__ ws,
                 const float* __restrict__ bf1,
                 const float* __restrict__ Wf2, const float* __restrict__ bf2,
                 const float* __restrict__ Wf3, const float* __restrict__ bf3,
                 float* __restrict__ out) {
    __shared__ float x1s[120];
    __shared__ float x2s[40];
    __shared__ int lastflag;
    int d = blockIdx.x;
    int t = threadIdx.x;
    int z = t >> 6, lane = t & 63;
    {
        const float* p = ws + PB_OFF + d * NBC + (z << 7);
        float s = p[lane] + p[64 + lane];
        #pragma unroll
        for (int off = 32; off; off >>= 1) s += __shfl_down(s, off);
        if (lane == 0) ws[X1PRE_OFF + d * 4 + z] = s;
    }
    __syncthreads();
    if (t == 0) {
        unsigned* ctr = reinterpret_cast<unsigned*>(ws + CTR_OFF);
        unsigned r = __hip_atomic_fetch_add(ctr, 1u, __ATOMIC_ACQ_REL,
                                            __HIP_MEMORY_SCOPE_AGENT);
        lastflag = (r == NHB - 1) ? 1 : 0;
    }
    __syncthreads();
    if (!lastflag) return;

    // -------- fc23 tail (last block only) --------
    if (t < 120) {                         // t = dd*4 + zz
        int dd = t >> 2, zz = t & 3;
        float x1 = ws[X1PRE_OFF + t]
                 + ws[BIAS_OFF + zz] * 0.03125f * ws[COLSUM_OFF + dd]
                 + bf1[dd];
        x1s[zz * 30 + dd] = fmaxf(x1, 0.f);
    }
    __syncthreads();
    if (t < 40) {
        int zz = t / 10, dd = t % 10;
        float sm = bf2[dd];
        #pragma unroll
        for (int kk = 0; kk < 30; ++kk)
            sm = fmaf(x1s[zz * 30 + kk], Wf2[kk * 10 + dd], sm);
        x2s[t] = fmaxf(sm, 0.f);
    }
    __syncthreads();
    if (t < 4) {
        float sm = bf3[0];
        #pragma unroll
        for (int kk = 0; kk < 10; ++kk)
            sm = fmaf(x2s[t * 10 + kk], Wf3[kk], sm);
        out[t] = sm;
    }
}

extern "C" void kernel_launch(void* const* d_in, const int* in_sizes, int n_in,
                              void* d_out, int out_size, void* d_ws, size_t ws_size,
                              hipStream_t stream) {
    const float* f   = (const float*)d_in[0];
    const float* geo = (const float*)d_in[1];
    const float* W1  = (const float*)d_in[2];
    const float* b1  = (const float*)d_in[3];
    const float* W2  = (const float*)d_in[4];
    const float* b2  = (const float*)d_in[5];
    const float* Wf1 = (const float*)d_in[6];
    const float* bf1 = (const float*)d_in[7];
    const float* Wf2 = (const float*)d_in[8];
    const float* bf2 = (const float*)d_in[9];
    const float* Wf3 = (const float*)d_in[10];
    const float* bf3 = (const float*)d_in[11];
    float* ws  = (float*)d_ws;
    float* out = (float*)d_out;

    hipLaunchKernelGGL(prep_kernel, dim3(99), dim3(256), 0, stream,
                       f, W1, b1, W2, b2, Wf1, ws);
    hipLaunchKernelGGL(conv_kernel, dim3(NBC), dim3(256), 0, stream,
                       f, geo, ws + UT_OFF,
                       reinterpret_cast<const float4*>(ws + WF1T_OFF),
                       ws + PB_OFF);
    hipLaunchKernelGGL(head_kernel, dim3(NHB), dim3(256), 0, stream,
                       ws, bf1, Wf2, bf2, Wf3, bf3, out);
}